// Round 7
// baseline (121.700 us; speedup 1.0000x reference)
//
#include <hip/hip_runtime.h>
#include <hip/hip_bf16.h>

// TripletLoss batch-hard mining, B=8192, D=256.
// R7: R6 minus ALL cross-block atomics. R6's WRITE_SIZE=20.7MB matched 1.33M
//     device-scope atomicMin/Max x 16B RMW exactly — memory-side atomic
//     serialization was eating the GEMM gains (R1 with plain stores did 2x
//     FLOPs in the same time). Now: write-once slot map, zero contention.
//     Row i (tile t): slot 2J+v from row-side of block (t,J); slot 2I+h from
//     col-side of block (I,t). 8192 x 128 float2 partials, reduced by finish.

constexpr int NB = 8192;
constexpr int NBT = NB / 128;                  // 64 tile-blocks per side
constexpr int NBLK = NBT * (NBT + 1) / 2;      // 2080

typedef __attribute__((ext_vector_type(8))) short bf16x8;
typedef __attribute__((ext_vector_type(4))) float f32x4;

typedef __attribute__((address_space(3))) unsigned int lds_u32;
typedef __attribute__((address_space(1))) const unsigned int g_u32;

__device__ inline void load_lds16(const unsigned short* g, unsigned short* l) {
    __builtin_amdgcn_global_load_lds((g_u32*)g, (lds_u32*)l, 16, 0, 0);
}

__device__ inline unsigned short f2bf(float v) {
    __hip_bfloat16 b = __float2bfloat16(v);
    return *reinterpret_cast<unsigned short*>(&b);
}

// key = sim + 8*min(|lr-lc|,1); pos keys in [-1.1,1.1], self-pairs forced to
// 6.0, neg keys in [6.9,9.1]. min(key)=hardest positive (min sim), max(key)=
// hardest negative. valid_pos <=> min<4.0 ; valid_neg <=> max>6.5.

// ---------------- Kernel 1: normalize rows -> bf16 chunk-major --------------
// Xbt 16B-unit index u = chunk*NB + row (chunk = k/8, 32 chunks of 8 elems).
__global__ __launch_bounds__(256) void norm_kernel(const float* __restrict__ X,
                                                   unsigned short* __restrict__ Xbt,
                                                   float* accum) {
    __shared__ float tile[32][260];
    __shared__ float psum[32][8];
    __shared__ float rscale[32];
    const int t = threadIdx.x;
    const int rb = blockIdx.x * 32;
    if (blockIdx.x == 0 && t == 0) { accum[0] = 0.f; accum[1] = 0.f; }
    #pragma unroll
    for (int k = 0; k < 8; k++) {
        const int f = k * 256 + t;
        const int row = f >> 6, c4 = f & 63;
        const float4 v = *((const float4*)(X + (size_t)(rb + row) * 256) + c4);
        *(float4*)&tile[row][c4 * 4] = v;
    }
    __syncthreads();
    {
        const int r = t >> 3, e = t & 7;
        float s = 0.f;
        #pragma unroll
        for (int i = 0; i < 32; i++) { const float v = tile[r][e * 32 + i]; s += v * v; }
        psum[r][e] = s;
    }
    __syncthreads();
    if (t < 32) {
        float s = 0.f;
        #pragma unroll
        for (int e = 0; e < 8; e++) s += psum[t][e];
        rscale[t] = 1.0f / fmaxf(sqrtf(s), 1e-12f);
    }
    __syncthreads();
    #pragma unroll
    for (int j = 0; j < 4; j++) {
        const int idx = j * 256 + t;
        const int q = idx >> 5, r = idx & 31;
        const float sc = rscale[r];
        unsigned short tmp[8];
        #pragma unroll
        for (int e = 0; e < 8; e++) tmp[e] = f2bf(tile[r][q * 8 + e] * sc);
        *(bf16x8*)(Xbt + ((size_t)q * NB + rb + r) * 8) = *(bf16x8*)tmp;
    }
}

// ---------------- Kernel 2: symmetric Gram + mining (slot stores) -----------
// Block = 128x128 tile, 4 waves in 2x2 (h=w&1 row-half, v=w>>1 col-half).
// K-loop kb=0..3 (BK=64) stages A+B (32 x 1KB regions) via global_load_lds;
// every ds_read_b128 is base + lane*16 (conflict-free).
__global__ __launch_bounds__(256) void mine_kernel(
    const unsigned short* __restrict__ Xbt, const int* __restrict__ labels,
    float2* __restrict__ Part) {
    __shared__ unsigned short Bt[32 * 512];   // 32 KB
    __shared__ float Lrow[128], Lcol[128];

    // triangle decode: blockIdx.x -> (Jblk=a, Iblk<=a)
    const int tb = blockIdx.x;
    int a = (int)((sqrtf(8.0f * (float)tb + 1.0f) - 1.0f) * 0.5f);
    while ((a + 1) * (a + 2) / 2 <= tb) a++;
    while (a * (a + 1) / 2 > tb) a--;
    const int Iblk = tb - a * (a + 1) / 2;
    const int Jblk = a;
    const bool isdiag = (Iblk == Jblk);
    const int Irow0 = Iblk * 128;
    const int Jcol0 = Jblk * 128;

    const int tid = threadIdx.x;
    const int w = tid >> 6;
    const int lane = tid & 63;
    const int quad = lane >> 4;
    const int l16 = lane & 15;
    const int h = w & 1;       // row half
    const int v = w >> 1;      // col half

    if (tid < 128) Lrow[tid] = (float)labels[Irow0 + tid];
    else Lcol[tid - 128] = (float)labels[Jcol0 + tid - 128];

    f32x4 acc[4][4];
    #pragma unroll
    for (int mi = 0; mi < 4; mi++)
        #pragma unroll
        for (int ni = 0; ni < 4; ni++) acc[mi][ni] = (f32x4){0.f, 0.f, 0.f, 0.f};

    for (int kb = 0; kb < 4; kb++) {
        __syncthreads();   // protect Bt (and order Lrow/Lcol on first iter)
        #pragma unroll
        for (int s = 0; s < 8; s++) {
            const int rg = w * 8 + s;           // 0..31
            const int r2 = rg & 15;
            const int ks = r2 >> 3;
            const int ti = r2 & 7;
            const int base = (rg >> 4) ? Jcol0 : Irow0;
            const int c = kb * 8 + ks * 4 + (lane >> 4);
            const size_t u = (size_t)c * NB + base + ti * 16 + l16;
            load_lds16(Xbt + u * 8, Bt + rg * 512);
        }
        __syncthreads();   // drains vmcnt incl. global_load_lds

        #pragma unroll
        for (int ks = 0; ks < 2; ks++) {
            bf16x8 af[4], bf[4];
            #pragma unroll
            for (int i = 0; i < 4; i++) {
                af[i] = *(const bf16x8*)(Bt + (ks * 8 + h * 4 + i) * 512 + lane * 8);
                bf[i] = *(const bf16x8*)(Bt + (16 + ks * 8 + v * 4 + i) * 512 + lane * 8);
            }
            #pragma unroll
            for (int mi = 0; mi < 4; mi++)
                #pragma unroll
                for (int ni = 0; ni < 4; ni++)
                    acc[mi][ni] = __builtin_amdgcn_mfma_f32_16x16x32_bf16(
                        af[mi], bf[ni], acc[mi][ni], 0, 0, 0);
        }
    }

    // ---- mining epilogue. C/D: row = quad*4+reg, col = l16 within 16-tile.
    const bool diagwave = isdiag && (h == v);
    float flc[4], cMin[4], cMax[4];
    #pragma unroll
    for (int ni = 0; ni < 4; ni++) {
        flc[ni] = Lcol[v * 64 + ni * 16 + l16];
        cMin[ni] = 1e30f;
        cMax[ni] = -1e30f;
    }
    #pragma unroll
    for (int mi = 0; mi < 4; mi++)
        #pragma unroll
        for (int r = 0; r < 4; r++) {
            const float flr = Lrow[h * 64 + mi * 16 + quad * 4 + r];
            float rMin = 1e30f, rMax = -1e30f;
            #pragma unroll
            for (int ni = 0; ni < 4; ni++) {
                const float uu = fminf(fabsf(flr - flc[ni]), 1.0f);
                float key = fmaf(uu, 8.0f, acc[mi][ni][r]);
                if (diagwave && mi == ni)   // neutralize exact self-pair
                    key = (l16 == quad * 4 + r) ? 6.0f : key;
                rMin = fminf(rMin, key);
                rMax = fmaxf(rMax, key);
                cMin[ni] = fminf(cMin[ni], key);
                cMax[ni] = fmaxf(cMax[ni], key);
            }
            #pragma unroll
            for (int m = 1; m <= 8; m <<= 1) {
                rMin = fminf(rMin, __shfl_xor(rMin, m, 64));
                rMax = fmaxf(rMax, __shfl_xor(rMax, m, 64));
            }
            if (l16 == 0) {   // write-once slot: row-side of (Iblk,Jblk), half v
                const int row = Irow0 + h * 64 + mi * 16 + quad * 4 + r;
                Part[(size_t)row * 128 + (Jblk * 2 + v)] = make_float2(rMin, rMax);
            }
        }
    if (!isdiag) {   // col-side (transpose contribution); diag covered above
        #pragma unroll
        for (int ni = 0; ni < 4; ni++) {
            float p = cMin[ni], n = cMax[ni];
            p = fminf(p, __shfl_xor(p, 16, 64));
            p = fminf(p, __shfl_xor(p, 32, 64));
            n = fmaxf(n, __shfl_xor(n, 16, 64));
            n = fmaxf(n, __shfl_xor(n, 32, 64));
            if (quad == 0) {  // write-once slot: col-side of (Iblk,Jblk), half h
                const int col = Jcol0 + v * 64 + ni * 16 + l16;
                Part[(size_t)col * 128 + (Iblk * 2 + h)] = make_float2(p, n);
            }
        }
    }
}

// ---------------- Kernel 3: per-row reduce + hinge + block sums -------------
__global__ __launch_bounds__(256) void finish1(const float2* __restrict__ Part,
                                               float* accum) {
    const int row = blockIdx.x * 256 + threadIdx.x;
    const float4* p4 = (const float4*)(Part + (size_t)row * 128);
    float mn = 1e30f, mx = -1e30f;
    #pragma unroll 8
    for (int s = 0; s < 64; s++) {
        const float4 vv = p4[s];
        mn = fminf(mn, fminf(vv.x, vv.z));
        mx = fmaxf(mx, fmaxf(vv.y, vv.w));
    }
    const bool valid = (mn < 4.0f) && (mx > 6.5f);
    const float pd = fmaxf(1.0f - mn, 0.0f);          // hardest-pos dist
    const float nd = fmaxf(1.0f - (mx - 8.0f), 0.0f); // hardest-neg dist
    float per = valid ? fmaxf(pd - nd + 1.0f, 0.0f) : 0.0f;
    float cnt = valid ? 1.0f : 0.0f;
    #pragma unroll
    for (int off = 32; off > 0; off >>= 1) {
        per += __shfl_down(per, off, 64);
        cnt += __shfl_down(cnt, off, 64);
    }
    __shared__ float sp[4], sc[4];
    const int wv = threadIdx.x >> 6, ln = threadIdx.x & 63;
    if (ln == 0) { sp[wv] = per; sc[wv] = cnt; }
    __syncthreads();
    if (threadIdx.x == 0) {
        atomicAdd(&accum[0], sp[0] + sp[1] + sp[2] + sp[3]);
        atomicAdd(&accum[1], sc[0] + sc[1] + sc[2] + sc[3]);
    }
}

__global__ void finish2(const float* __restrict__ accum, float* __restrict__ out) {
    const float s = accum[0], c = accum[1];
    out[0] = (c > 0.f) ? s / fmaxf(c, 1.f) : 0.f;
}

// ---------------- launcher --------------------------------------------------
extern "C" void kernel_launch(void* const* d_in, const int* in_sizes, int n_in,
                              void* d_out, int out_size, void* d_ws, size_t ws_size,
                              hipStream_t stream) {
    const float* X = (const float*)d_in[0];
    const int* labels = (const int*)d_in[1];
    float* out = (float*)d_out;

    char* ws = (char*)d_ws;
    unsigned short* Xbt = (unsigned short*)ws;                    // 4 MB
    float2* Part = (float2*)(ws + (size_t)4 * 1024 * 1024);       // 8 MB
    float* accum = (float*)(ws + (size_t)12 * 1024 * 1024);       // 8 B

    norm_kernel<<<NB / 32, 256, 0, stream>>>(X, Xbt, accum);
    mine_kernel<<<NBLK, 256, 0, stream>>>(
        (const unsigned short*)Xbt, labels, Part);
    finish1<<<NB / 256, 256, 0, stream>>>(Part, accum);
    finish2<<<1, 1, 0, stream>>>(accum, out);
}